// Round 9
// baseline (101.447 us; speedup 1.0000x reference)
//
#include <hip/hip_runtime.h>

#define D        128
#define KCODES   2048
#define NROWS    32768
#define BATCH    8192

typedef _Float16 f16x8  __attribute__((ext_vector_type(8)));
typedef float    f32x16 __attribute__((ext_vector_type(16)));

#define MFMA(a, b, c) __builtin_amdgcn_mfma_f32_32x32x16_f16((a), (b), (c), 0, 0, 0)
#define INV2048 4.8828125e-4f

static __device__ __forceinline__ f32x16 zero16() {
    f32x16 z;
#pragma unroll
    for (int i = 0; i < 16; ++i) z[i] = 0.0f;
    return z;
}

static __device__ __forceinline__ void gload16(const void* g, void* l) {
    __builtin_amdgcn_global_load_lds(
        (const __attribute__((address_space(1))) unsigned int*)g,
        (__attribute__((address_space(3))) unsigned int*)l, 16, 0, 0);
}

// ---------------------------------------------------------------------------
// Kernel A: W -> (wh, wl) fp16 hi/lo, fragment-linear layout + fp32 ||W||^2.
// Lane mapping (verified R2-R8): for 32-code block n0, kstep ks, lane l holds
// W[n0*32 + (l&31)][ks*16 + (l>>5)*8 + j], stored at f16x8 idx ((n0*8+ks)*64+l).
// ---------------------------------------------------------------------------
__global__ void wconv_kernel(const float* __restrict__ W,
                             _Float16* __restrict__ whf, _Float16* __restrict__ wlf,
                             float* __restrict__ wnorm) {
    int gid = blockIdx.x * 256 + threadIdx.x;    // 32768 = 2048 codes x 16 slots
    int n = gid >> 4, s = gid & 15;
    const float4* src = (const float4*)(W + (size_t)n * D + s * 8);
    float4 a = src[0], b = src[1];
    float va[8] = {a.x, a.y, a.z, a.w, b.x, b.y, b.z, b.w};
    f16x8 hi, lo;
    float ss = 0.0f;
#pragma unroll
    for (int j = 0; j < 8; ++j) {
        _Float16 h = (_Float16)va[j];
        hi[j] = h;
        lo[j] = (_Float16)((va[j] - (float)h) * 2048.0f);
        ss += va[j] * va[j];
    }
    int ks = s >> 1, sub = s & 1;
    size_t idx = ((size_t)((n >> 5) * 8 + ks) * 64 + sub * 32 + (n & 31));
    ((f16x8*)whf)[idx] = hi;
    ((f16x8*)wlf)[idx] = lo;
#pragma unroll
    for (int m = 1; m <= 8; m <<= 1) ss += __shfl_xor(ss, m);
    if (s == 0) wnorm[n] = ss;
}

// ---------------------------------------------------------------------------
// Kernel B: fused MFMA scores + argmin — W-STATIONARY, BARRIER-FREE.
// Grid 512 = 64 row-groups x 8 code-octants (oct = b & 7 -> XCD-local panel).
// Block 512 thr = 8 waves; LDS: octant panel wh 64KB | wl 64KB | wnorm 1KB
// staged ONCE (one __syncthreads, then none). 1 block/CU, 2 waves/SIMD,
// full 256-VGPR budget. Each wave: 2 passes x 32 rows; per nl-block (32
// codes): 16 ds_read_b128 + 24 MFMA on 3 independent acc chains. Waves
// drift freely -> no convoy. Per-octant argmin partials to bsp/bcp[8][N].
// ---------------------------------------------------------------------------
extern "C" __global__ void __launch_bounds__(512)
__attribute__((amdgpu_flat_work_group_size(512, 512)))
__attribute__((amdgpu_waves_per_eu(2, 2)))
vq_argmin(const float* __restrict__ f,
          const _Float16* __restrict__ whf, const _Float16* __restrict__ wlf,
          const float* __restrict__ wnorm,
          float* __restrict__ bsp, int* __restrict__ bcp) {
    extern __shared__ unsigned char lds[];   // wh 64KB | wl @65536 | wnorm @131072

    const int b   = blockIdx.x;
    const int oct = b & 7;                   // code octant 0..7 (XCD-local)
    const int rg  = b >> 3;                  // row group 0..63 (512 rows)
    const int tid = threadIdx.x;
    const int w   = tid >> 6, l = tid & 63;
    const int l31 = l & 31, lh = l >> 5;

    // ---- stage octant panel (128KB + 1KB wnorm) once ----
    {
        const char* gh = (const char*)whf + (size_t)oct * 65536;
        const char* gl = (const char*)wlf + (size_t)oct * 65536;
#pragma unroll
        for (int u = 0; u < 8; ++u) {
            gload16(gh + u * 8192 + tid * 16, lds + u * 8192 + tid * 16);
            gload16(gl + u * 8192 + tid * 16, lds + 65536 + u * 8192 + tid * 16);
        }
        if (tid < 64)
            gload16((const char*)wnorm + oct * 1024 + tid * 16,
                    lds + 131072 + tid * 16);
    }
    __syncthreads();                         // the ONLY barrier

    const float* wnL = (const float*)(lds + 131072);

#pragma unroll 1
    for (int pass = 0; pass < 2; ++pass) {
        const int rowsBase = rg * 512 + pass * 256 + w * 32;

        // ---- A-fragments: 32 rows of f in hi/lo fp16 (64 VGPR) ----
        f16x8 fh[8], fl[8];
#pragma unroll
        for (int ks = 0; ks < 8; ++ks) {
            const float4* p = (const float4*)(f + (size_t)(rowsBase + l31) * D
                                              + ks * 16 + lh * 8);
            float4 a = p[0], bb = p[1];
            float va[8] = {a.x, a.y, a.z, a.w, bb.x, bb.y, bb.z, bb.w};
            f16x8 hi, lo;
#pragma unroll
            for (int j = 0; j < 8; ++j) {
                _Float16 h = (_Float16)va[j];
                hi[j] = h;
                lo[j] = (_Float16)((va[j] - (float)h) * 2048.0f);
            }
            fh[ks] = hi;
            fl[ks] = lo;
        }

        float bestP[16];
#pragma unroll
        for (int e = 0; e < 16; ++e) bestP[e] = 3.4e38f;

        // ---- main loop: 8 nl-blocks, no syncs, compiler pipelines ----
#pragma unroll 2
        for (int nl = 0; nl < 8; ++nl) {
            const unsigned char* wbh = lds + nl * 8192;
            const unsigned char* wbl = lds + 65536 + nl * 8192;
            f32x16 accC0 = zero16(), accC1 = zero16(), accH = zero16();
#pragma unroll
            for (int ks = 0; ks < 8; ++ks) {
                f16x8 wh = *(const f16x8*)(wbh + ks * 1024 + l * 16);
                f16x8 wl = *(const f16x8*)(wbl + ks * 1024 + l * 16);
                accC0 = MFMA(fh[ks], wl, accC0);   // 3 independent chains
                accH  = MFMA(fh[ks], wh, accH);
                accC1 = MFMA(fl[ks], wh, accC1);
            }
            const float wv = wnL[nl * 32 + l31];
#pragma unroll
            for (int r = 0; r < 16; ++r) {
                float sc = fmaf(accC0[r] + accC1[r], INV2048, accH[r]);
                float s  = fmaf(-2.0f, sc, wv);
                unsigned p = (__float_as_uint(s) & 0xFFFFFFF0u) | (unsigned)nl;
                bestP[r] = fminf(bestP[r], __uint_as_float(p));
            }
        }

        // ---- butterfly over the 32 code-columns; write octant partials ----
#pragma unroll
        for (int e = 0; e < 16; ++e) {
            float s = bestP[e];
            int nlE = (int)(__float_as_uint(s) & 15u);
            int c   = oct * 256 + nlE * 32 + l31;
#pragma unroll
            for (int msk = 1; msk <= 16; msk <<= 1) {
                float s2 = __shfl_xor(s, msk);
                int   c2 = __shfl_xor(c, msk);
                if (s2 < s || (s2 == s && c2 < c)) { s = s2; c = c2; }
            }
            if (l31 == 0) {
                int row = (e & 3) + 8 * (e >> 2) + 4 * lh;   // 0..31
                bsp[(size_t)oct * NROWS + rowsBase + row] = s;
                bcp[(size_t)oct * NROWS + rowsBase + row] = c;
            }
        }
    }
}

// ---------------------------------------------------------------------------
// Kernel C: merge the 8 octant partials, gather W[j], write out + loss.
// ---------------------------------------------------------------------------
__global__ void gather_kernel(const float* __restrict__ f, const float* __restrict__ W,
                              const float* __restrict__ bsp, const int* __restrict__ bcp,
                              float* __restrict__ loss, float* __restrict__ outv) {
    int b  = blockIdx.x;
    int wv = threadIdx.x >> 6;
    int l  = threadIdx.x & 63;
    int n  = b * 4 + wv;
    float s; int c;
    if (l < 8) { s = bsp[(size_t)l * NROWS + n]; c = bcp[(size_t)l * NROWS + n]; }
    else       { s = 3.4e38f; c = 0x7FFFFFFF; }
#pragma unroll
    for (int msk = 1; msk <= 4; msk <<= 1) {
        float s2 = __shfl_xor(s, msk);
        int   c2 = __shfl_xor(c, msk);
        if (s2 < s || (s2 == s && c2 < c)) { s = s2; c = c2; }
    }
    int j = __shfl(c, 0);            // lanes 0..7 hold the 8-octant min
    float2 fv = reinterpret_cast<const float2*>(f + (size_t)n * D)[l];
    float2 wj = reinterpret_cast<const float2*>(W + (size_t)j * D)[l];
    reinterpret_cast<float2*>(outv + (size_t)n * D)[l] = wj;
    float dx = fv.x - wj.x, dy = fv.y - wj.y;
    float ls = dx * dx + dy * dy;
#pragma unroll
    for (int off = 32; off; off >>= 1) ls += __shfl_down(ls, off);
    __shared__ float lsm[4];
    if (l == 0) lsm[wv] = ls;
    __syncthreads();
    if (threadIdx.x == 0)
        loss[b] = 1.25f * 0.25f * (lsm[0] + lsm[1] + lsm[2] + lsm[3]);
}

// ---------------------------------------------------------------------------
extern "C" void kernel_launch(void* const* d_in, const int* in_sizes, int n_in,
                              void* d_out, int out_size, void* d_ws, size_t ws_size,
                              hipStream_t stream) {
    const float* f = (const float*)d_in[0];   // [8192,512] -> 32768 rows of 128
    const float* W = (const float*)d_in[1];   // [2048,128]

    float* loss = (float*)d_out;              // [8192]
    float* outv = (float*)d_out + BATCH;      // [8192*512]

    // workspace layout
    float*    wnorm = (float*)d_ws;                              // @0       (8 KB)
    _Float16* whf   = (_Float16*)((char*)d_ws + 8192);           // @8K    (512 KB)
    _Float16* wlf   = (_Float16*)((char*)d_ws + 532480);         // @520K  (512 KB)
    float*    bsp   = (float*)((char*)d_ws + 1056768);           // @1032K   (1 MB)
    int*      bcp   = (int*)((char*)d_ws + 2105344);             // @2056K   (1 MB)

    wconv_kernel<<<KCODES * 16 / 256, 256, 0, stream>>>(W, whf, wlf, wnorm);

    hipLaunchKernelGGL(vq_argmin, dim3(512), dim3(512), 132096, stream,
                       f, whf, wlf, wnorm, bsp, bcp);

    gather_kernel<<<BATCH, 256, 0, stream>>>(f, W, bsp, bcp, loss, outv);
}

// Round 10
// 83.324 us; speedup vs baseline: 1.2175x; 1.2175x over previous
//
#include <hip/hip_runtime.h>

#define D        128
#define KCODES   2048
#define NROWS    32768
#define BATCH    8192

typedef _Float16 f16x8  __attribute__((ext_vector_type(8)));
typedef float    f32x16 __attribute__((ext_vector_type(16)));

#define MFMA(a, b, c) __builtin_amdgcn_mfma_f32_32x32x16_f16((a), (b), (c), 0, 0, 0)
#define INV2048 4.8828125e-4f

static __device__ __forceinline__ void gload16(const void* g, void* l) {
    __builtin_amdgcn_global_load_lds(
        (const __attribute__((address_space(1))) unsigned int*)g,
        (__attribute__((address_space(3))) unsigned int*)l, 16, 0, 0);
}

// ---------------------------------------------------------------------------
// Kernel A: W -> (wh, wl) fp16 hi/lo, fragment-linear layout + fp32 ||W||^2.
// Lane mapping (verified R2-R9): for 32-code block n0, kstep ks, lane l holds
// W[n0*32 + (l&31)][ks*16 + (l>>5)*8 + j], stored at f16x8 idx ((n0*8+ks)*64+l).
// ---------------------------------------------------------------------------
__global__ void wconv_kernel(const float* __restrict__ W,
                             _Float16* __restrict__ whf, _Float16* __restrict__ wlf,
                             float* __restrict__ wnorm) {
    int gid = blockIdx.x * 256 + threadIdx.x;    // 32768 = 2048 codes x 16 slots
    int n = gid >> 4, s = gid & 15;
    const float4* src = (const float4*)(W + (size_t)n * D + s * 8);
    float4 a = src[0], b = src[1];
    float va[8] = {a.x, a.y, a.z, a.w, b.x, b.y, b.z, b.w};
    f16x8 hi, lo;
    float ss = 0.0f;
#pragma unroll
    for (int j = 0; j < 8; ++j) {
        _Float16 h = (_Float16)va[j];
        hi[j] = h;
        lo[j] = (_Float16)((va[j] - (float)h) * 2048.0f);
        ss += va[j] * va[j];
    }
    int ks = s >> 1, sub = s & 1;
    size_t idx = ((size_t)((n >> 5) * 8 + ks) * 64 + sub * 32 + (n & 31));
    ((f16x8*)whf)[idx] = hi;
    ((f16x8*)wlf)[idx] = lo;
#pragma unroll
    for (int m = 1; m <= 8; m <<= 1) ss += __shfl_xor(ss, m);
    if (s == 0) wnorm[n] = ss;
}

// ---------------------------------------------------------------------------
// Kernel B: fused MFMA scores + argmin — 8 INDEPENDENT ACC CHAINS per wave.
// Grid 512 = 128 row-blocks(256 rows) x 4 code-quarters(512 codes).
// Block 512 thr = 8 waves x 32 rows; each wave covers ALL 128 codes of a
// chunk as 4 col-tiles x {accC, accH} = 8 chains (same-chain gap >= 8 MFMA).
// A-frags hold -2*f (hi/lo fp16) so scores need no -2 at fold; accH inits
// with wnorm -> fold = fmaf+and+or+min (4 ops). 4 chunks of 128 codes,
// 2x64KB LDS dbuf + 2KB wnorm = 130KB, 1 block/CU, vmcnt(0)+barrier/chunk.
// ---------------------------------------------------------------------------
extern "C" __global__ void __launch_bounds__(512)
__attribute__((amdgpu_flat_work_group_size(512, 512)))
__attribute__((amdgpu_waves_per_eu(2, 2)))
vq_argmin(const float* __restrict__ f,
          const _Float16* __restrict__ whf, const _Float16* __restrict__ wlf,
          const float* __restrict__ wnorm,
          float* __restrict__ bsp, int* __restrict__ bcp) {
    extern __shared__ unsigned char lds[];   // [2][65536] dbuf | wnorm @131072

    const int b   = blockIdx.x;
    const int qrt = b & 3;                   // code quarter (512 codes)
    const int rb  = b >> 2;                  // row block 0..127 (256 rows)
    const int tid = threadIdx.x;
    const int w   = tid >> 6, l = tid & 63;
    const int l31 = l & 31, lh = l >> 5;
    const int rowsBase = rb * 256 + w * 32;

    const char* ghB = (const char*)whf + (size_t)(qrt * 16) * 8192;
    const char* glB = (const char*)wlf + (size_t)(qrt * 16) * 8192;

    // chunk c (128 codes = 4 n0-blocks = 32KB hi + 32KB lo)
#define STAGE(c) {                                                          \
        unsigned char* dB = lds + ((c) & 1) * 65536;                        \
        const char* gh = ghB + (size_t)(c) * 32768;                         \
        const char* gl = glB + (size_t)(c) * 32768;                         \
        gload16(gh + tid * 16,         dB + tid * 16);                      \
        gload16(gh + 8192  + tid * 16, dB + 8192  + tid * 16);              \
        gload16(gh + 16384 + tid * 16, dB + 16384 + tid * 16);              \
        gload16(gh + 24576 + tid * 16, dB + 24576 + tid * 16);              \
        gload16(gl + tid * 16,         dB + 32768 + tid * 16);              \
        gload16(gl + 8192  + tid * 16, dB + 40960 + tid * 16);              \
        gload16(gl + 16384 + tid * 16, dB + 49152 + tid * 16);              \
        gload16(gl + 24576 + tid * 16, dB + 57344 + tid * 16);              \
    }

    STAGE(0);
    if (tid < 128)
        gload16((const char*)wnorm + qrt * 2048 + tid * 16,
                lds + 131072 + tid * 16);

    // ---- A-fragments: 32 rows of (-2*f) in hi/lo fp16 (64 VGPR) ----
    f16x8 fh[8], fl[8];
#pragma unroll
    for (int ks = 0; ks < 8; ++ks) {
        const float4* p = (const float4*)(f + (size_t)(rowsBase + l31) * D
                                          + ks * 16 + lh * 8);
        float4 a = p[0], bb = p[1];
        float va[8] = {a.x, a.y, a.z, a.w, bb.x, bb.y, bb.z, bb.w};
        f16x8 hi, lo;
#pragma unroll
        for (int j = 0; j < 8; ++j) {
            float x = -2.0f * va[j];
            _Float16 h = (_Float16)x;
            hi[j] = h;
            lo[j] = (_Float16)((x - (float)h) * 2048.0f);
        }
        fh[ks] = hi;
        fl[ks] = lo;
    }

    __syncthreads();     // chunk 0 + wnorm staged; all vmcnt drained

    const float* wnL = (const float*)(lds + 131072);

    float bestP[16];
#pragma unroll
    for (int e = 0; e < 16; ++e) bestP[e] = 3.4e38f;

#pragma unroll 1
    for (int t = 0; t < 4; ++t) {
        if (t > 0) {
            asm volatile("s_waitcnt vmcnt(0)" ::: "memory");
            __builtin_amdgcn_s_barrier();
            asm volatile("" ::: "memory");
        }
        if (t < 3) STAGE(t + 1);

        const unsigned char* wb = lds + (t & 1) * 65536;

        // per-column wnorm (col = l31 within each 32-code tile)
        float wv[4];
#pragma unroll
        for (int j = 0; j < 4; ++j) wv[j] = wnL[t * 128 + j * 32 + l31];

        // 8 independent chains: accC[j] (cross, init 0), accH[j] (hi, init wn)
        f32x16 accC[4], accH[4];
#pragma unroll
        for (int j = 0; j < 4; ++j)
#pragma unroll
            for (int r = 0; r < 16; ++r) { accC[j][r] = 0.0f; accH[j][r] = wv[j]; }

#pragma unroll
        for (int ks = 0; ks < 8; ++ks) {
            f16x8 wh[4], wl[4];
#pragma unroll
            for (int j = 0; j < 4; ++j) {
                wh[j] = *(const f16x8*)(wb + ((j * 8 + ks) << 10) + l * 16);
                wl[j] = *(const f16x8*)(wb + 32768 + ((j * 8 + ks) << 10) + l * 16);
            }
            // Ca x4, H x4, Cb x4 -> same-chain gap >= 8 MFMAs
#pragma unroll
            for (int j = 0; j < 4; ++j) accC[j] = MFMA(fh[ks], wl[j], accC[j]);
#pragma unroll
            for (int j = 0; j < 4; ++j) accH[j] = MFMA(fh[ks], wh[j], accH[j]);
#pragma unroll
            for (int j = 0; j < 4; ++j) accC[j] = MFMA(fl[ks], wh[j], accC[j]);
        }

        // ---- fold: s = accH + accC/2048; pack (t,j) in low 4 bits ----
#pragma unroll
        for (int j = 0; j < 4; ++j) {
            const unsigned mv = (unsigned)(t * 4 + j);
#pragma unroll
            for (int r = 0; r < 16; ++r) {
                float s = fmaf(accC[j][r], INV2048, accH[j][r]);
                unsigned p = (__float_as_uint(s) & 0xFFFFFFF0u) | mv;
                bestP[r] = fminf(bestP[r], __uint_as_float(p));
            }
        }
    }
#undef STAGE

    // ---- butterfly over the 32 code-columns; write quarter partials ----
    // (waves own disjoint rows -> no cross-wave merge needed)
#pragma unroll
    for (int e = 0; e < 16; ++e) {
        float s = bestP[e];
        unsigned m = __float_as_uint(s) & 15u;
        int c = qrt * 512 + (int)(m >> 2) * 128 + (int)(m & 3) * 32 + l31;
#pragma unroll
        for (int msk = 1; msk <= 16; msk <<= 1) {
            float s2 = __shfl_xor(s, msk);
            int   c2 = __shfl_xor(c, msk);
            if (s2 < s || (s2 == s && c2 < c)) { s = s2; c = c2; }
        }
        if (l31 == 0) {
            int row = (e & 3) + 8 * (e >> 2) + 4 * lh;   // 0..31
            bsp[(size_t)qrt * NROWS + rowsBase + row] = s;
            bcp[(size_t)qrt * NROWS + rowsBase + row] = c;
        }
    }
}

// ---------------------------------------------------------------------------
// Kernel C: merge the 4 quarter partials, gather W[j], write out + loss.
// ---------------------------------------------------------------------------
__global__ void gather_kernel(const float* __restrict__ f, const float* __restrict__ W,
                              const float* __restrict__ bsp, const int* __restrict__ bcp,
                              float* __restrict__ loss, float* __restrict__ outv) {
    int b  = blockIdx.x;
    int wv = threadIdx.x >> 6;
    int l  = threadIdx.x & 63;
    int n  = b * 4 + wv;
    float s; int c;
    if (l < 4) { s = bsp[(size_t)l * NROWS + n]; c = bcp[(size_t)l * NROWS + n]; }
    else       { s = 3.4e38f; c = 0x7FFFFFFF; }
#pragma unroll
    for (int msk = 1; msk <= 2; msk <<= 1) {
        float s2 = __shfl_xor(s, msk);
        int   c2 = __shfl_xor(c, msk);
        if (s2 < s || (s2 == s && c2 < c)) { s = s2; c = c2; }
    }
    int j = __shfl(c, 0);
    float2 fv = reinterpret_cast<const float2*>(f + (size_t)n * D)[l];
    float2 wj = reinterpret_cast<const float2*>(W + (size_t)j * D)[l];
    reinterpret_cast<float2*>(outv + (size_t)n * D)[l] = wj;
    float dx = fv.x - wj.x, dy = fv.y - wj.y;
    float ls = dx * dx + dy * dy;
#pragma unroll
    for (int off = 32; off; off >>= 1) ls += __shfl_down(ls, off);
    __shared__ float lsm[4];
    if (l == 0) lsm[wv] = ls;
    __syncthreads();
    if (threadIdx.x == 0)
        loss[b] = 1.25f * 0.25f * (lsm[0] + lsm[1] + lsm[2] + lsm[3]);
}

// ---------------------------------------------------------------------------
extern "C" void kernel_launch(void* const* d_in, const int* in_sizes, int n_in,
                              void* d_out, int out_size, void* d_ws, size_t ws_size,
                              hipStream_t stream) {
    const float* f = (const float*)d_in[0];   // [8192,512] -> 32768 rows of 128
    const float* W = (const float*)d_in[1];   // [2048,128]

    float* loss = (float*)d_out;              // [8192]
    float* outv = (float*)d_out + BATCH;      // [8192*512]

    // workspace layout
    float*    wnorm = (float*)d_ws;                              // @0       (8 KB)
    _Float16* whf   = (_Float16*)((char*)d_ws + 8192);           // @8K    (512 KB)
    _Float16* wlf   = (_Float16*)((char*)d_ws + 532480);         // @520K  (512 KB)
    float*    bsp   = (float*)((char*)d_ws + 1056768);           //        (512 KB)
    int*      bcp   = (int*)((char*)d_ws + 1581056);             //        (512 KB)

    wconv_kernel<<<KCODES * 16 / 256, 256, 0, stream>>>(W, whf, wlf, wnorm);

    hipLaunchKernelGGL(vq_argmin, dim3(512), dim3(512), 133120, stream,
                       f, whf, wlf, wnorm, bsp, bcp);

    gather_kernel<<<BATCH, 256, 0, stream>>>(f, W, bsp, bcp, loss, outv);
}